// Round 5
// baseline (199.880 us; speedup 1.0000x reference)
//
#include <hip/hip_runtime.h>
#include <hip/hip_cooperative_groups.h>

namespace cg = cooperative_groups;

// N=8, C=256, H=W=64, A=9, bs=8, F=8, K=64, M=A*N*K=4608
constexpr int N_ = 8, C_ = 256, H_ = 64, W_ = 64, A_ = 9, F_ = 8, K_ = 64;
constexpr int M_ = A_ * N_ * K_;
constexpr int NPOS = 512;                  // N*F*F positions
constexpr int NJOBS = A_ * N_ * (C_ / 16); // 1152 rois jobs
constexpr int PSTRIDE = 9 * 256;           // per-position partials: [9 anchors][256 ch]
#define ALPHA_BS 0.8f                      // ALPHA(0.1) * bs(8)
#define L2E 1.442695040888963f

// LDS arena: Phase B tile[256][65] fp32 (66560 B) + sW/sI; rois uses 13 KB of it
constexpr int SH_BYTES = 256 * 65 * 4 + 9 * 16 + 9 * 16;

// ---------------------------------------------------------------------------
// Phase A: conv partials, W register-stationary. unit = (g, chunk):
// g = (n,gy) 0..63, chunk = 32-channel slice 0..7 (== XCD at 512-grid).
// Thread t = (cl=t>>3, r=t&7) owns W[a][c][r][0..7] in regs (18 float4).
// Loop gx: 2 feat float4 loads, 9x8 FMA, 3-shfl row reduce, store per-channel
// partial to partials[p][a][c]  (collision-free: c = chunk*32+cl is global).
// ---------------------------------------------------------------------------
__device__ __forceinline__ void phaseA(const float* __restrict__ feat,
                                       const float* __restrict__ Wreg,
                                       float* __restrict__ partials,
                                       int unit, int t) {
    const int chunk = unit & 7;
    const int g = unit >> 3;
    const int n = g >> 3, gy = g & 7;
    const int r = t & 7;
    const int c = chunk * 32 + (t >> 3);

    const float* wp = Wreg + chunk * 2048 + t * 8;
    float4 w0[9], w1[9];
#pragma unroll
    for (int a = 0; a < 9; ++a) {
        w0[a] = *(const float4*)(wp + (size_t)a * 16384);
        w1[a] = *(const float4*)(wp + (size_t)a * 16384 + 4);
    }
    const float* frow = feat + (((size_t)n * C_ + c) * H_ + gy * 8 + r) * W_;
#pragma unroll 1
    for (int i = 0; i < 8; ++i) {          // gx = i
        const float4 f0 = *(const float4*)(frow + i * 8);
        const float4 f1 = *(const float4*)(frow + i * 8 + 4);
        float* pp = partials + (size_t)(g * 8 + i) * PSTRIDE + c;
#pragma unroll
        for (int a = 0; a < 9; ++a) {
            float s = f0.x * w0[a].x + f0.y * w0[a].y + f0.z * w0[a].z + f0.w * w0[a].w;
            s = fmaf(f1.x, w1[a].x, s);
            s = fmaf(f1.y, w1[a].y, s);
            s = fmaf(f1.z, w1[a].z, s);
            s = fmaf(f1.w, w1[a].w, s);
            s += __shfl_xor(s, 1, 64);     // sum 8 patch rows (lane bits 0..2)
            s += __shfl_xor(s, 2, 64);
            s += __shfl_xor(s, 4, 64);
            if (r == 0) pp[a * 256] = s;   // per-channel partial
        }
    }
}

// ---------------------------------------------------------------------------
// Phase B: finish conv (72 threads: 8 per anchor), tanh offsets, stage
// 256c x 8x8 tile [c][65] (write & read <=2-way banks), bilinear sample.
// Offsets bounded by +-0.8 => corners stay inside this 8x8 block.
// ---------------------------------------------------------------------------
__device__ __forceinline__ void phaseB(const float* __restrict__ feat,
                                       const float* __restrict__ partials,
                                       const float* __restrict__ breg,
                                       float* __restrict__ rfb,
                                       int b, int t, char* sh) {
    const int n = b >> 6, gy = (b >> 3) & 7, gx = b & 7;
    float (*tile)[65] = (float(*)[65])sh;
    float (*sW)[4] = (float(*)[4])(sh + 66560);
    int   (*sI)[4] = (int(*)[4])(sh + 66560 + 144);

    if (t < 72) {
        const int a = t >> 3, q = t & 7;
        const float* pp = partials + (size_t)b * PSTRIDE + a * 256 + q * 32;
        float s = 0.f;
#pragma unroll
        for (int k = 0; k < 8; ++k) {
            float4 v = *(const float4*)(pp + k * 4);
            s += v.x + v.y + v.z + v.w;
        }
        s += __shfl_xor(s, 1, 64);         // sum the 8 q-slices
        s += __shfl_xor(s, 2, 64);
        s += __shfl_xor(s, 4, 64);
        if (q == 0) {
            float rr  = s + breg[a];
            float off = ALPHA_BS * tanhf(rr);
            float cx = 3.5f + 8.0f * gx + off;
            float cy = 3.5f + 8.0f * gy + off;
            float x0f = floorf(cx), y0f = floorf(cy);
            float wx = cx - x0f, wy = cy - y0f;
            int x0 = min(max((int)x0f, 0), W_ - 1);
            int x1 = min(x0 + 1, W_ - 1);
            int y0 = min(max((int)y0f, 0), H_ - 1);
            int y1 = min(y0 + 1, H_ - 1);
            int lx0 = x0 - gx * 8, lx1 = x1 - gx * 8;
            int ly0 = y0 - gy * 8, ly1 = y1 - gy * 8;
            sI[a][0] = ly0 * 8 + lx0;
            sI[a][1] = ly0 * 8 + lx1;
            sI[a][2] = ly1 * 8 + lx0;
            sI[a][3] = ly1 * 8 + lx1;
            sW[a][0] = (1.f - wx) * (1.f - wy);
            sW[a][1] = wx * (1.f - wy);
            sW[a][2] = (1.f - wx) * wy;
            sW[a][3] = wx * wy;
        }
    }

    const float* fb = feat + ((size_t)n * C_ * H_ + gy * 8) * W_ + gx * 8;
#pragma unroll
    for (int it = 0; it < 16; ++it) {
        int q = t + 256 * it;
        int c = q >> 4, r = (q >> 1) & 7, h = q & 1;
        float4 v = *(const float4*)(fb + ((size_t)c * H_ + r) * W_ + h * 4);
        int e = r * 8 + h * 4;
        tile[c][e + 0] = v.x;
        tile[c][e + 1] = v.y;
        tile[c][e + 2] = v.z;
        tile[c][e + 3] = v.w;
    }
    __syncthreads();

    const int kidx = gy * 8 + gx;
#pragma unroll
    for (int a = 0; a < 9; ++a) {
        float v = sW[a][0] * tile[t][sI[a][0]] + sW[a][1] * tile[t][sI[a][1]] +
                  sW[a][2] * tile[t][sI[a][2]] + sW[a][3] * tile[t][sI[a][3]];
        rfb[((size_t)(a * N_ + n) * K_ + kidx) * C_ + t] = v;
    }
    __syncthreads();   // tile/sW dead before reuse
}

// ---------------------------------------------------------------------------
// rois job: out[j] = b[j] + softmax_i(a_i b_j) . a  for 16 channels of one
// (n,a) pair. In-place-safe (block reads exactly what it writes, staged).
// ---------------------------------------------------------------------------
__device__ __forceinline__ void rois_job(const float* f1, const float* f2,
                                         float* out, int j, int t, int lane,
                                         int w, char* sh) {
    float (*sa)[17] = (float(*)[17])sh;
    float (*sb)[17] = (float(*)[17])(sh + 4352);
    float (*so)[17] = (float(*)[17])(sh + 8704);
    const int na = j >> 4;
    const int cb = (j & 15) * 16;
    const size_t base = (size_t)na * 64;
#pragma unroll
    for (int k = 0; k < 4; ++k) {
        int idx = t + 256 * k;
        int i = idx >> 4, cc = idx & 15;
        sa[i][cc] = f1[(base + i) * 256 + cb + cc];
        sb[i][cc] = f2[(base + i) * 256 + cb + cc];
    }
    __syncthreads();
#pragma unroll
    for (int ci = 0; ci < 4; ++ci) {
        const int cc = w * 4 + ci;
        const float a_ = sa[lane][cc];
        const float b_ = sb[lane][cc];
        float mx = a_, mn = a_;
#pragma unroll
        for (int s = 32; s; s >>= 1) {
            mx = fmaxf(mx, __shfl_xor(mx, s, 64));
            mn = fminf(mn, __shfl_xor(mn, s, 64));
        }
        const float m   = b_ > 0.f ? b_ * mx : b_ * mn;
        const float bl2 = b_ * L2E;
        const float ml2 = -m * L2E;
        float den = 0.f, num = 0.f;
#pragma unroll
        for (int i = 0; i < 64; ++i) {
            const float ai = __int_as_float(__builtin_amdgcn_readlane(__float_as_int(a_), i));
            const float e  = __builtin_amdgcn_exp2f(fmaf(ai, bl2, ml2));
            den += e;
            num = fmaf(e, ai, num);
        }
        so[lane][cc] = b_ + num / den;
    }
    __syncthreads();
#pragma unroll
    for (int k = 0; k < 4; ++k) {
        int idx = t + 256 * k;
        int i = idx >> 4, cc = idx & 15;
        out[(base + i) * 256 + cb + cc] = so[i][cc];
    }
    __syncthreads();
}

// ---------------------------------------------------------------------------
// Cooperative fused pipeline (all phases grid-stride; grid size runtime).
// ---------------------------------------------------------------------------
__global__ __launch_bounds__(256, 2) void k_fused(const float* __restrict__ feat,
                                                  const float* __restrict__ Wreg,
                                                  const float* __restrict__ breg,
                                                  const float* __restrict__ rois_a,
                                                  const float* __restrict__ rois_c,
                                                  float* out, float* ws) {
    __shared__ __align__(16) char sh[SH_BYTES];
    float* partials = ws;                       // [512][9][256]
    float* rfb      = ws + (size_t)NPOS * PSTRIDE;

    cg::grid_group grid = cg::this_grid();
    const int t = threadIdx.x, lane = t & 63, wid = t >> 6;
    const int nb = gridDim.x;

    for (int u = blockIdx.x; u < NPOS; u += nb) phaseA(feat, Wreg, partials, u, t);
    grid.sync();
    for (int u = blockIdx.x; u < NPOS; u += nb)
        phaseB(feat, partials, breg, rfb, (u & 7) * 64 + (u >> 3), t, sh);
    grid.sync();
    for (int j = blockIdx.x; j < NJOBS; j += nb) rois_job(rois_a, rfb, out, j, t, lane, wid, sh);
    grid.sync();
    for (int j = blockIdx.x; j < NJOBS; j += nb) rois_job(out, rois_c, out, j, t, lane, wid, sh);
}

// ---------------------------------------------------------------------------
// Fallback (non-cooperative) kernels — same device code, 4 launches.
// ---------------------------------------------------------------------------
__global__ __launch_bounds__(256, 2) void kA(const float* __restrict__ feat,
                                             const float* __restrict__ Wreg,
                                             float* __restrict__ partials) {
    for (int u = blockIdx.x; u < NPOS; u += gridDim.x)
        phaseA(feat, Wreg, partials, u, threadIdx.x);
}
__global__ __launch_bounds__(256, 2) void kB(const float* __restrict__ feat,
                                             const float* __restrict__ partials,
                                             const float* __restrict__ breg,
                                             float* __restrict__ rfb) {
    __shared__ __align__(16) char sh[SH_BYTES];
    for (int u = blockIdx.x; u < NPOS; u += gridDim.x)
        phaseB(feat, partials, breg, rfb, (u & 7) * 64 + (u >> 3), threadIdx.x, sh);
}
__global__ __launch_bounds__(256) void kR(const float* f1, const float* __restrict__ f2,
                                          float* out) {
    __shared__ __align__(16) char sh[3 * 4352];
    const int t = threadIdx.x;
    for (int j = blockIdx.x; j < NJOBS; j += gridDim.x)
        rois_job(f1, f2, out, j, t, t & 63, t >> 6, sh);
}

// ---------------------------------------------------------------------------
extern "C" void kernel_launch(void* const* d_in, const int* in_sizes, int n_in,
                              void* d_out, int out_size, void* d_ws, size_t ws_size,
                              hipStream_t stream) {
    // inputs: ori_feature_shape, rois_feature_a, feature_b, rois_feature_c, W_reg, b_reg
    const float* rois_a = (const float*)d_in[1];
    const float* feat   = (const float*)d_in[2];
    const float* rois_c = (const float*)d_in[3];
    const float* Wreg   = (const float*)d_in[4];
    const float* breg   = (const float*)d_in[5];
    float* out = (float*)d_out;
    float* ws  = (float*)d_ws;   // 512*2304 partials (4.7MB) + M*C rfb (4.7MB)

    // Cooperative path: grid = co-resident capacity (deterministic query).
    int perCU = 0;
    hipError_t qe = hipOccupancyMaxActiveBlocksPerMultiprocessor(
        &perCU, (const void*)k_fused, 256, 0);
    int nblk = (qe == hipSuccess && perCU > 0) ? min(512, perCU * 256) : 0;

    hipError_t le = hipErrorUnknown;
    if (nblk > 0) {
        void* args[] = {(void*)&feat, (void*)&Wreg, (void*)&breg,
                        (void*)&rois_a, (void*)&rois_c, (void*)&out, (void*)&ws};
        le = hipLaunchCooperativeKernel((const void*)k_fused, dim3(nblk), dim3(256),
                                        args, 0, stream);
    }
    if (le != hipSuccess) {
        // Deterministic fallback: 4 regular launches.
        float* partials = ws;
        float* rfb = ws + (size_t)NPOS * PSTRIDE;
        kA<<<dim3(NPOS), dim3(256), 0, stream>>>(feat, Wreg, partials);
        kB<<<dim3(NPOS), dim3(256), 0, stream>>>(feat, partials, breg, rfb);
        kR<<<dim3(NJOBS), dim3(256), 0, stream>>>(rois_a, rfb, out);
        kR<<<dim3(NJOBS), dim3(256), 0, stream>>>(out, rois_c, out);
    }
}

// Round 6
// 64.968 us; speedup vs baseline: 3.0766x; 3.0766x over previous
//
#include <hip/hip_runtime.h>

// N=8, C=256, H=W=64, A=9, bs=8, F=8, K=64, M=A*N*K=4608
constexpr int N_ = 8, C_ = 256, H_ = 64, W_ = 64, A_ = 9, F_ = 8, K_ = 64;
constexpr int M_ = A_ * N_ * K_;
constexpr int NPOS = 512;                  // N*F*F positions
constexpr int NJOBS = A_ * N_ * (C_ / 16); // 1152 rois jobs
constexpr int PSTRIDE = 9 * 256;           // per-position partials: [9 anchors][256 ch]
#define ALPHA_BS 0.8f                      // ALPHA(0.1) * bs(8)
#define L2E 1.442695040888963f

// ---------------------------------------------------------------------------
// kA: conv partials, W register-stationary. 512 blocks = (g, chunk):
// g = (n,gy) 0..63, chunk = 32-channel slice 0..7 (== XCD id -> each XCD L2
// holds its 73.7KB W slice + its feat channel slice). Thread t = (cl=t>>3,
// r=t&7) holds W[a][c][r][0..7] in regs (18 float4) across 8 gx positions:
// W traffic 302 -> 37.7 MB. Per gx: 2 feat float4 loads, 72 FMA, 3-shfl row
// reduce, per-channel partial store to partials[p][a][c] (collision-free).
// No LDS -> full wave-slot occupancy for latency hiding.
// ---------------------------------------------------------------------------
__global__ __launch_bounds__(256) void kA(const float* __restrict__ feat,
                                          const float* __restrict__ Wreg,
                                          float* __restrict__ partials) {
    const int bi = blockIdx.x;
    const int chunk = bi & 7;
    const int g = bi >> 3;
    const int n = g >> 3, gy = g & 7;
    const int t = threadIdx.x;
    const int r = t & 7;
    const int c = chunk * 32 + (t >> 3);

    const float* wp = Wreg + chunk * 2048 + t * 8;
    float4 w0[9], w1[9];
#pragma unroll
    for (int a = 0; a < 9; ++a) {
        w0[a] = *(const float4*)(wp + (size_t)a * 16384);
        w1[a] = *(const float4*)(wp + (size_t)a * 16384 + 4);
    }
    const float* frow = feat + (((size_t)n * C_ + c) * H_ + gy * 8 + r) * W_;
#pragma unroll 2
    for (int i = 0; i < 8; ++i) {          // gx = i
        const float4 f0 = *(const float4*)(frow + i * 8);
        const float4 f1 = *(const float4*)(frow + i * 8 + 4);
        float* pp = partials + (size_t)(g * 8 + i) * PSTRIDE + c;
#pragma unroll
        for (int a = 0; a < 9; ++a) {
            float s = f0.x * w0[a].x + f0.y * w0[a].y + f0.z * w0[a].z + f0.w * w0[a].w;
            s = fmaf(f1.x, w1[a].x, s);
            s = fmaf(f1.y, w1[a].y, s);
            s = fmaf(f1.z, w1[a].z, s);
            s = fmaf(f1.w, w1[a].w, s);
            s += __shfl_xor(s, 1, 64);     // sum 8 patch rows (lane bits 0..2)
            s += __shfl_xor(s, 2, 64);
            s += __shfl_xor(s, 4, 64);
            if (r == 0) pp[a * 256] = s;   // per-channel partial
        }
    }
}

// ---------------------------------------------------------------------------
// kB: finish conv (72 threads: 8 per anchor, float4 reads + 3-shfl), tanh
// offsets, stage 256c x 8x8 tile [c][65] (65%32==1 -> write ~2-way, read
// conflict-free), bilinear sample, coalesced rfb store.
// Offsets bounded by +-0.8 => corners stay inside this 8x8 block.
// ---------------------------------------------------------------------------
__global__ __launch_bounds__(256, 2) void kB(const float* __restrict__ feat,
                                             const float* __restrict__ partials,
                                             const float* __restrict__ breg,
                                             float* __restrict__ rfb) {
    __shared__ float tile[256][65];
    __shared__ float sW[9][4];
    __shared__ int   sI[9][4];

    const int bi = blockIdx.x;
    const int b  = (bi & 7) * 64 + (bi >> 3);   // XCD x -> image n = x
    const int n = b >> 6, gy = (b >> 3) & 7, gx = b & 7;
    const int t = threadIdx.x;

    if (t < 72) {
        const int a = t >> 3, q = t & 7;
        const float* pp = partials + (size_t)b * PSTRIDE + a * 256 + q * 32;
        float s = 0.f;
#pragma unroll
        for (int k = 0; k < 8; ++k) {
            float4 v = *(const float4*)(pp + k * 4);
            s += v.x + v.y + v.z + v.w;
        }
        s += __shfl_xor(s, 1, 64);         // sum the 8 q-slices
        s += __shfl_xor(s, 2, 64);
        s += __shfl_xor(s, 4, 64);
        if (q == 0) {
            float rr  = s + breg[a];
            float off = ALPHA_BS * tanhf(rr);
            float cx = 3.5f + 8.0f * gx + off;
            float cy = 3.5f + 8.0f * gy + off;
            float x0f = floorf(cx), y0f = floorf(cy);
            float wx = cx - x0f, wy = cy - y0f;
            int x0 = min(max((int)x0f, 0), W_ - 1);
            int x1 = min(x0 + 1, W_ - 1);
            int y0 = min(max((int)y0f, 0), H_ - 1);
            int y1 = min(y0 + 1, H_ - 1);
            int lx0 = x0 - gx * 8, lx1 = x1 - gx * 8;
            int ly0 = y0 - gy * 8, ly1 = y1 - gy * 8;
            sI[a][0] = ly0 * 8 + lx0;
            sI[a][1] = ly0 * 8 + lx1;
            sI[a][2] = ly1 * 8 + lx0;
            sI[a][3] = ly1 * 8 + lx1;
            sW[a][0] = (1.f - wx) * (1.f - wy);
            sW[a][1] = wx * (1.f - wy);
            sW[a][2] = (1.f - wx) * wy;
            sW[a][3] = wx * wy;
        }
    }

    const float* fb = feat + ((size_t)n * C_ * H_ + gy * 8) * W_ + gx * 8;
#pragma unroll
    for (int it = 0; it < 16; ++it) {
        int q = t + 256 * it;
        int c = q >> 4, r = (q >> 1) & 7, h = q & 1;
        float4 v = *(const float4*)(fb + ((size_t)c * H_ + r) * W_ + h * 4);
        int e = r * 8 + h * 4;
        tile[c][e + 0] = v.x;
        tile[c][e + 1] = v.y;
        tile[c][e + 2] = v.z;
        tile[c][e + 3] = v.w;
    }
    __syncthreads();

    const int kidx = gy * 8 + gx;
#pragma unroll
    for (int a = 0; a < 9; ++a) {
        float v = sW[a][0] * tile[t][sI[a][0]] + sW[a][1] * tile[t][sI[a][1]] +
                  sW[a][2] * tile[t][sI[a][2]] + sW[a][3] * tile[t][sI[a][3]];
        rfb[((size_t)(a * N_ + n) * K_ + kidx) * C_ + t] = v;
    }
}

// ---------------------------------------------------------------------------
// kR: rois_to_rois. 1152 blocks = (na, 16-channel chunk), XCD-swizzled.
// Stage a,b [64][17] in LDS (coalesced); wave w handles 4 channels, lane = j;
// inner K-loop broadcasts a_i via readlane, e = exp2(fma). Staged coalesced
// writeback. Stage 2 runs in place on d_out: each block reads exactly the
// region it overwrites (barrier-ordered). 13 KB LDS -> ~4 blocks/CU.
// ---------------------------------------------------------------------------
__global__ __launch_bounds__(256) void kR(const float* f1,
                                          const float* __restrict__ f2,
                                          float* out) {
    __shared__ float sa[64][17];
    __shared__ float sb[64][17];
    __shared__ float so[64][17];

    const int bi = blockIdx.x;
    const int j  = (bi & 7) * 144 + (bi >> 3);  // XCD-chunked
    const int na = j >> 4;
    const int cb = (j & 15) * 16;
    const int t = threadIdx.x, lane = t & 63, w = t >> 6;
    const size_t base = (size_t)na * 64;

#pragma unroll
    for (int k = 0; k < 4; ++k) {
        int idx = t + 256 * k;
        int i = idx >> 4, cc = idx & 15;
        sa[i][cc] = f1[(base + i) * 256 + cb + cc];
        sb[i][cc] = f2[(base + i) * 256 + cb + cc];
    }
    __syncthreads();

#pragma unroll
    for (int ci = 0; ci < 4; ++ci) {
        const int cc = w * 4 + ci;
        const float a_ = sa[lane][cc];
        const float b_ = sb[lane][cc];
        float mx = a_, mn = a_;
#pragma unroll
        for (int s = 32; s; s >>= 1) {
            mx = fmaxf(mx, __shfl_xor(mx, s, 64));
            mn = fminf(mn, __shfl_xor(mn, s, 64));
        }
        const float m   = b_ > 0.f ? b_ * mx : b_ * mn;
        const float bl2 = b_ * L2E;
        const float ml2 = -m * L2E;
        float den = 0.f, num = 0.f;
#pragma unroll
        for (int i = 0; i < 64; ++i) {
            const float ai = __int_as_float(__builtin_amdgcn_readlane(__float_as_int(a_), i));
            const float e  = __builtin_amdgcn_exp2f(fmaf(ai, bl2, ml2));
            den += e;
            num = fmaf(e, ai, num);
        }
        so[lane][cc] = b_ + num / den;
    }
    __syncthreads();

#pragma unroll
    for (int k = 0; k < 4; ++k) {
        int idx = t + 256 * k;
        int i = idx >> 4, cc = idx & 15;
        out[(base + i) * 256 + cb + cc] = so[i][cc];
    }
}

// ---------------------------------------------------------------------------
extern "C" void kernel_launch(void* const* d_in, const int* in_sizes, int n_in,
                              void* d_out, int out_size, void* d_ws, size_t ws_size,
                              hipStream_t stream) {
    // inputs: ori_feature_shape, rois_feature_a, feature_b, rois_feature_c, W_reg, b_reg
    const float* rois_a = (const float*)d_in[1];
    const float* feat   = (const float*)d_in[2];
    const float* rois_c = (const float*)d_in[3];
    const float* Wreg   = (const float*)d_in[4];
    const float* breg   = (const float*)d_in[5];
    float* out = (float*)d_out;
    float* partials = (float*)d_ws;                         // 512*2304 fl = 4.7 MB
    float* rfb      = (float*)d_ws + (size_t)NPOS * PSTRIDE; // M*C fl = 4.7 MB

    kA<<<dim3(NPOS), dim3(256), 0, stream>>>(feat, Wreg, partials);
    kB<<<dim3(NPOS), dim3(256), 0, stream>>>(feat, partials, breg, rfb);
    kR<<<dim3(NJOBS), dim3(256), 0, stream>>>(rois_a, rfb, out);
    kR<<<dim3(NJOBS), dim3(256), 0, stream>>>(out, rois_c, out);
}

// Round 7
// 61.943 us; speedup vs baseline: 3.2269x; 1.0488x over previous
//
#include <hip/hip_runtime.h>

// N=8, C=256, H=W=64, A=9, bs=8, F=8, K=64, M=A*N*K=4608
constexpr int N_ = 8, C_ = 256, H_ = 64, W_ = 64, A_ = 9, F_ = 8, K_ = 64;
constexpr int M_ = A_ * N_ * K_;
constexpr int NPOS = 512;                  // N*F*F positions
constexpr int NJOBS = A_ * N_ * (C_ / 16); // 1152 rois jobs
constexpr int PSTRIDE = 9 * 256;           // per-position partials: [9 anchors][256 ch]
#define ALPHA_BS 0.8f                      // ALPHA(0.1) * bs(8)
#define L2E 1.442695040888963f

// ---------------------------------------------------------------------------
// kA: conv partials, W register-stationary. 2048 blocks = (pair, g, chunk):
// chunk = bi&7 == XCD id (same-chunk blocks share one XCD's L2: 74KB W slice
// + feat channel slice stay hot); g = (n,gy); pair picks 2 of 8 gx.
// 2048 blocks -> 4 blocks/CU resident (VGPR-capped) = 4x the latency hiding
// of R6's 512-block version. Thread t = (cl=t>>3, r=t&7) holds
// W[a][c][r][0..7] in regs (18 float4). Per gx: 2 feat float4 loads, 72 FMA,
// 3-shfl row reduce, per-channel partial store (collision-free). No LDS.
// ---------------------------------------------------------------------------
__global__ __launch_bounds__(256) void kA(const float* __restrict__ feat,
                                          const float* __restrict__ Wreg,
                                          float* __restrict__ partials) {
    const int bi = blockIdx.x;
    const int chunk = bi & 7;
    const int g = (bi >> 3) & 63;
    const int pair = bi >> 9;              // 0..3
    const int n = g >> 3, gy = g & 7;
    const int t = threadIdx.x;
    const int r = t & 7;
    const int c = chunk * 32 + (t >> 3);

    const float* wp = Wreg + chunk * 2048 + t * 8;
    float4 w0[9], w1[9];
#pragma unroll
    for (int a = 0; a < 9; ++a) {
        w0[a] = *(const float4*)(wp + (size_t)a * 16384);
        w1[a] = *(const float4*)(wp + (size_t)a * 16384 + 4);
    }
    const float* frow = feat + (((size_t)n * C_ + c) * H_ + gy * 8 + r) * W_;
#pragma unroll
    for (int i = 0; i < 2; ++i) {
        const int gx = pair * 2 + i;
        const float4 f0 = *(const float4*)(frow + gx * 8);
        const float4 f1 = *(const float4*)(frow + gx * 8 + 4);
        float* pp = partials + (size_t)(g * 8 + gx) * PSTRIDE + c;
#pragma unroll
        for (int a = 0; a < 9; ++a) {
            float s = f0.x * w0[a].x + f0.y * w0[a].y + f0.z * w0[a].z + f0.w * w0[a].w;
            s = fmaf(f1.x, w1[a].x, s);
            s = fmaf(f1.y, w1[a].y, s);
            s = fmaf(f1.z, w1[a].z, s);
            s = fmaf(f1.w, w1[a].w, s);
            s += __shfl_xor(s, 1, 64);     // sum 8 patch rows (lane bits 0..2)
            s += __shfl_xor(s, 2, 64);
            s += __shfl_xor(s, 4, 64);
            if (r == 0) pp[a * 256] = s;   // per-channel partial
        }
    }
}

// ---------------------------------------------------------------------------
// kB: finish conv + tanh offsets + bilinear sample, channel-split.
// 1024 blocks = (position, c-half): tile[128][65] = 33.3KB -> 4 blocks/CU.
// 72 threads reduce partials (8 per anchor: 8 float4 + 3 shfl) -> offsets;
// all threads stage 128ch x 8x8 tile (write ~2-way, read conflict-free);
// waves 0-1 sample anchors 0-4, waves 2-3 anchors 5-8 (wave-uniform bounds).
// Offsets bounded by +-0.8 => corners stay inside this 8x8 block.
// ---------------------------------------------------------------------------
__global__ __launch_bounds__(256, 4) void kB(const float* __restrict__ feat,
                                             const float* __restrict__ partials,
                                             const float* __restrict__ breg,
                                             float* __restrict__ rfb) {
    __shared__ float tile[128][65];
    __shared__ float sW[9][4];
    __shared__ int   sI[9][4];

    const int bi = blockIdx.x;
    const int u  = (bi & 7) * 128 + (bi >> 3);  // XCD x -> image n = x
    const int b = u >> 1, half = u & 1;
    const int n = b >> 6, gy = (b >> 3) & 7, gx = b & 7;
    const int t = threadIdx.x;

    if (t < 72) {
        const int a = t >> 3, q = t & 7;
        const float* pp = partials + (size_t)b * PSTRIDE + a * 256 + q * 32;
        float s = 0.f;
#pragma unroll
        for (int k = 0; k < 8; ++k) {
            float4 v = *(const float4*)(pp + k * 4);
            s += v.x + v.y + v.z + v.w;
        }
        s += __shfl_xor(s, 1, 64);         // sum the 8 q-slices
        s += __shfl_xor(s, 2, 64);
        s += __shfl_xor(s, 4, 64);
        if (q == 0) {
            float rr  = s + breg[a];
            float off = ALPHA_BS * tanhf(rr);
            float cx = 3.5f + 8.0f * gx + off;
            float cy = 3.5f + 8.0f * gy + off;
            float x0f = floorf(cx), y0f = floorf(cy);
            float wx = cx - x0f, wy = cy - y0f;
            int x0 = min(max((int)x0f, 0), W_ - 1);
            int x1 = min(x0 + 1, W_ - 1);
            int y0 = min(max((int)y0f, 0), H_ - 1);
            int y1 = min(y0 + 1, H_ - 1);
            int lx0 = x0 - gx * 8, lx1 = x1 - gx * 8;
            int ly0 = y0 - gy * 8, ly1 = y1 - gy * 8;
            sI[a][0] = ly0 * 8 + lx0;
            sI[a][1] = ly0 * 8 + lx1;
            sI[a][2] = ly1 * 8 + lx0;
            sI[a][3] = ly1 * 8 + lx1;
            sW[a][0] = (1.f - wx) * (1.f - wy);
            sW[a][1] = wx * (1.f - wy);
            sW[a][2] = (1.f - wx) * wy;
            sW[a][3] = wx * wy;
        }
    }

    const float* fb = feat + (((size_t)n * C_ + half * 128) * H_ + gy * 8) * W_ + gx * 8;
#pragma unroll
    for (int it = 0; it < 8; ++it) {
        int q = t + 256 * it;
        int c = q >> 4, rr = (q >> 1) & 7, h = q & 1;
        float4 v = *(const float4*)(fb + ((size_t)c * H_ + rr) * W_ + h * 4);
        int e = rr * 8 + h * 4;
        tile[c][e + 0] = v.x;
        tile[c][e + 1] = v.y;
        tile[c][e + 2] = v.z;
        tile[c][e + 3] = v.w;
    }
    __syncthreads();

    const int kidx = gy * 8 + gx;
    const int cl = t & 127;
    const int p = t >> 7;                  // wave-pair: anchors 0-4 / 5-8
    for (int a = p ? 5 : 0; a < (p ? 9 : 5); ++a) {
        float v = sW[a][0] * tile[cl][sI[a][0]] + sW[a][1] * tile[cl][sI[a][1]] +
                  sW[a][2] * tile[cl][sI[a][2]] + sW[a][3] * tile[cl][sI[a][3]];
        rfb[((size_t)(a * N_ + n) * K_ + kidx) * C_ + half * 128 + cl] = v;
    }
}

// ---------------------------------------------------------------------------
// kRf: BOTH rois_to_rois stages fused. Job (na, 16-ch chunk): stage-2's a
// input is exactly stage-1's output for the same (j=lane, cc) — kept in a
// REGISTER (o1), no global round-trip, no second kernel. rois_c prefetched
// to regs during stage 1. Single write to d_out.
// ---------------------------------------------------------------------------
__global__ __launch_bounds__(256) void kRf(const float* __restrict__ rois_a,
                                           const float* __restrict__ rfb,
                                           const float* __restrict__ rois_c,
                                           float* __restrict__ out) {
    __shared__ float sa[64][17];
    __shared__ float sb[64][17];
    __shared__ float sc[64][17];

    const int bi = blockIdx.x;
    const int j  = (bi & 7) * 144 + (bi >> 3);  // XCD-chunked
    const int na = j >> 4;
    const int cb = (j & 15) * 16;
    const int t = threadIdx.x, lane = t & 63, w = t >> 6;
    const size_t base = (size_t)na * 64;

    float rc[4];
#pragma unroll
    for (int k = 0; k < 4; ++k) {
        int idx = t + 256 * k;
        int i = idx >> 4, cc = idx & 15;
        sa[i][cc] = rois_a[(base + i) * 256 + cb + cc];
        sb[i][cc] = rfb[(base + i) * 256 + cb + cc];
        rc[k]     = rois_c[(base + i) * 256 + cb + cc];
    }
    __syncthreads();

    // ---- stage 1: a = rois_a (sa), b = sampled (sb) -> o1 in registers ----
    float o1[4];
#pragma unroll
    for (int ci = 0; ci < 4; ++ci) {
        const int cc = w * 4 + ci;
        const float a_ = sa[lane][cc];
        const float b_ = sb[lane][cc];
        float mx = a_, mn = a_;
#pragma unroll
        for (int s = 32; s; s >>= 1) {
            mx = fmaxf(mx, __shfl_xor(mx, s, 64));
            mn = fminf(mn, __shfl_xor(mn, s, 64));
        }
        const float m   = b_ > 0.f ? b_ * mx : b_ * mn;
        const float bl2 = b_ * L2E;
        const float ml2 = -m * L2E;
        float den = 0.f, num = 0.f;
#pragma unroll
        for (int i = 0; i < 64; ++i) {
            const float ai = __int_as_float(__builtin_amdgcn_readlane(__float_as_int(a_), i));
            const float e  = __builtin_amdgcn_exp2f(fmaf(ai, bl2, ml2));
            den += e;
            num = fmaf(e, ai, num);
        }
        o1[ci] = b_ + num / den;
    }
    __syncthreads();           // sb reads done; safe to overwrite

#pragma unroll
    for (int k = 0; k < 4; ++k) {
        int idx = t + 256 * k;
        sb[idx >> 4][idx & 15] = rc[k];    // sb <- rois_c
    }
    __syncthreads();

    // ---- stage 2: a = o1 (registers!), b = rois_c (sb) -> sc -> d_out ----
#pragma unroll
    for (int ci = 0; ci < 4; ++ci) {
        const int cc = w * 4 + ci;
        const float a_ = o1[ci];
        const float b_ = sb[lane][cc];
        float mx = a_, mn = a_;
#pragma unroll
        for (int s = 32; s; s >>= 1) {
            mx = fmaxf(mx, __shfl_xor(mx, s, 64));
            mn = fminf(mn, __shfl_xor(mn, s, 64));
        }
        const float m   = b_ > 0.f ? b_ * mx : b_ * mn;
        const float bl2 = b_ * L2E;
        const float ml2 = -m * L2E;
        float den = 0.f, num = 0.f;
#pragma unroll
        for (int i = 0; i < 64; ++i) {
            const float ai = __int_as_float(__builtin_amdgcn_readlane(__float_as_int(a_), i));
            const float e  = __builtin_amdgcn_exp2f(fmaf(ai, bl2, ml2));
            den += e;
            num = fmaf(e, ai, num);
        }
        sc[lane][cc] = b_ + num / den;
    }
    __syncthreads();

#pragma unroll
    for (int k = 0; k < 4; ++k) {
        int idx = t + 256 * k;
        int i = idx >> 4, cc = idx & 15;
        out[(base + i) * 256 + cb + cc] = sc[i][cc];
    }
}

// ---------------------------------------------------------------------------
extern "C" void kernel_launch(void* const* d_in, const int* in_sizes, int n_in,
                              void* d_out, int out_size, void* d_ws, size_t ws_size,
                              hipStream_t stream) {
    // inputs: ori_feature_shape, rois_feature_a, feature_b, rois_feature_c, W_reg, b_reg
    const float* rois_a = (const float*)d_in[1];
    const float* feat   = (const float*)d_in[2];
    const float* rois_c = (const float*)d_in[3];
    const float* Wreg   = (const float*)d_in[4];
    const float* breg   = (const float*)d_in[5];
    float* out = (float*)d_out;
    float* partials = (float*)d_ws;                          // 512*2304 fl = 4.7 MB
    float* rfb      = (float*)d_ws + (size_t)NPOS * PSTRIDE; // M*C fl = 4.7 MB

    kA<<<dim3(NPOS * 4), dim3(256), 0, stream>>>(feat, Wreg, partials);
    kB<<<dim3(NPOS * 2), dim3(256), 0, stream>>>(feat, partials, breg, rfb);
    kRf<<<dim3(NJOBS), dim3(256), 0, stream>>>(rois_a, rfb, rois_c, out);
}

// Round 8
// 50.881 us; speedup vs baseline: 3.9284x; 1.2174x over previous
//
#include <hip/hip_runtime.h>

// N=8, C=256, H=W=64, A=9, bs=8, F=8, K=64, M=A*N*K=4608
constexpr int N_ = 8, C_ = 256, H_ = 64, W_ = 64, A_ = 9, F_ = 8, K_ = 64;
constexpr int M_ = A_ * N_ * K_;
constexpr int NPOS = 512;                  // N*F*F positions
constexpr int PSTRIDE = 9 * 256;           // per-position partials: [9 anchors][256 ch]
constexpr int NJOBS2 = A_ * N_ * (C_ / 8); // 2304 fused-rois jobs (8 ch each)
#define ALPHA_BS 0.8f                      // ALPHA(0.1) * bs(8)
#define L2E 1.442695040888963f

typedef float f32x2 __attribute__((ext_vector_type(2)));

// ---------------------------------------------------------------------------
// kA: conv partials, W register-stationary. 2048 blocks = (pair, g, chunk):
// chunk = bi&7 == XCD id; g = (n,gy); pair picks 2 of 8 gx. Thread t =
// (cl=t>>3, r=t&7) holds W[a][c][r][0..7] in regs (18 float4). Per gx:
// 2 feat float4 loads, 72 FMA, 3-shfl row reduce, per-channel partial store.
// ---------------------------------------------------------------------------
__global__ __launch_bounds__(256) void kA(const float* __restrict__ feat,
                                          const float* __restrict__ Wreg,
                                          float* __restrict__ partials) {
    const int bi = blockIdx.x;
    const int chunk = bi & 7;
    const int g = (bi >> 3) & 63;
    const int pair = bi >> 9;              // 0..3
    const int n = g >> 3, gy = g & 7;
    const int t = threadIdx.x;
    const int r = t & 7;
    const int c = chunk * 32 + (t >> 3);

    const float* wp = Wreg + chunk * 2048 + t * 8;
    float4 w0[9], w1[9];
#pragma unroll
    for (int a = 0; a < 9; ++a) {
        w0[a] = *(const float4*)(wp + (size_t)a * 16384);
        w1[a] = *(const float4*)(wp + (size_t)a * 16384 + 4);
    }
    const float* frow = feat + (((size_t)n * C_ + c) * H_ + gy * 8 + r) * W_;
#pragma unroll
    for (int i = 0; i < 2; ++i) {
        const int gx = pair * 2 + i;
        const float4 f0 = *(const float4*)(frow + gx * 8);
        const float4 f1 = *(const float4*)(frow + gx * 8 + 4);
        float* pp = partials + (size_t)(g * 8 + gx) * PSTRIDE + c;
#pragma unroll
        for (int a = 0; a < 9; ++a) {
            float s = f0.x * w0[a].x + f0.y * w0[a].y + f0.z * w0[a].z + f0.w * w0[a].w;
            s = fmaf(f1.x, w1[a].x, s);
            s = fmaf(f1.y, w1[a].y, s);
            s = fmaf(f1.z, w1[a].z, s);
            s = fmaf(f1.w, w1[a].w, s);
            s += __shfl_xor(s, 1, 64);     // sum 8 patch rows (lane bits 0..2)
            s += __shfl_xor(s, 2, 64);
            s += __shfl_xor(s, 4, 64);
            if (r == 0) pp[a * 256] = s;   // per-channel partial
        }
    }
}

// ---------------------------------------------------------------------------
// kB: finish conv + tanh offsets + bilinear sample, channel-split.
// 1024 blocks = (position, c-half): tile[128][65] = 33.3KB -> 4 blocks/CU.
// Offsets bounded by +-0.8 => corners stay inside this 8x8 block.
// ---------------------------------------------------------------------------
__global__ __launch_bounds__(256, 4) void kB(const float* __restrict__ feat,
                                             const float* __restrict__ partials,
                                             const float* __restrict__ breg,
                                             float* __restrict__ rfb) {
    __shared__ float tile[128][65];
    __shared__ float sW[9][4];
    __shared__ int   sI[9][4];

    const int bi = blockIdx.x;
    const int u  = (bi & 7) * 128 + (bi >> 3);  // XCD x -> image n = x
    const int b = u >> 1, half = u & 1;
    const int n = b >> 6, gy = (b >> 3) & 7, gx = b & 7;
    const int t = threadIdx.x;

    if (t < 72) {
        const int a = t >> 3, q = t & 7;
        const float* pp = partials + (size_t)b * PSTRIDE + a * 256 + q * 32;
        float s = 0.f;
#pragma unroll
        for (int k = 0; k < 8; ++k) {
            float4 v = *(const float4*)(pp + k * 4);
            s += v.x + v.y + v.z + v.w;
        }
        s += __shfl_xor(s, 1, 64);         // sum the 8 q-slices
        s += __shfl_xor(s, 2, 64);
        s += __shfl_xor(s, 4, 64);
        if (q == 0) {
            float rr  = s + breg[a];
            float off = ALPHA_BS * tanhf(rr);
            float cx = 3.5f + 8.0f * gx + off;
            float cy = 3.5f + 8.0f * gy + off;
            float x0f = floorf(cx), y0f = floorf(cy);
            float wx = cx - x0f, wy = cy - y0f;
            int x0 = min(max((int)x0f, 0), W_ - 1);
            int x1 = min(x0 + 1, W_ - 1);
            int y0 = min(max((int)y0f, 0), H_ - 1);
            int y1 = min(y0 + 1, H_ - 1);
            int lx0 = x0 - gx * 8, lx1 = x1 - gx * 8;
            int ly0 = y0 - gy * 8, ly1 = y1 - gy * 8;
            sI[a][0] = ly0 * 8 + lx0;
            sI[a][1] = ly0 * 8 + lx1;
            sI[a][2] = ly1 * 8 + lx0;
            sI[a][3] = ly1 * 8 + lx1;
            sW[a][0] = (1.f - wx) * (1.f - wy);
            sW[a][1] = wx * (1.f - wy);
            sW[a][2] = (1.f - wx) * wy;
            sW[a][3] = wx * wy;
        }
    }

    const float* fb = feat + (((size_t)n * C_ + half * 128) * H_ + gy * 8) * W_ + gx * 8;
#pragma unroll
    for (int it = 0; it < 8; ++it) {
        int q = t + 256 * it;
        int c = q >> 4, rr = (q >> 1) & 7, h = q & 1;
        float4 v = *(const float4*)(fb + ((size_t)c * H_ + rr) * W_ + h * 4);
        int e = rr * 8 + h * 4;
        tile[c][e + 0] = v.x;
        tile[c][e + 1] = v.y;
        tile[c][e + 2] = v.z;
        tile[c][e + 3] = v.w;
    }
    __syncthreads();

    const int kidx = gy * 8 + gx;
    const int cl = t & 127;
    const int p = t >> 7;                  // wave-pair: anchors 0-4 / 5-8
    for (int a = p ? 5 : 0; a < (p ? 9 : 5); ++a) {
        float v = sW[a][0] * tile[cl][sI[a][0]] + sW[a][1] * tile[cl][sI[a][1]] +
                  sW[a][2] * tile[cl][sI[a][2]] + sW[a][3] * tile[cl][sI[a][3]];
        rfb[((size_t)(a * N_ + n) * K_ + kidx) * C_ + half * 128 + cl] = v;
    }
}

// ---------------------------------------------------------------------------
// kRf: both rois stages fused. 2304 blocks = (na, 8-ch chunk) -> 9216 waves
// (~8/SIMD with VGPR<=64). Wave w owns channel PAIR cp=2w; lane = j.
// a_i broadcast = ONE uniform ds_read_b64 per i (both channels); arithmetic
// on f32x2 so clang can pack v_pk_fma_f32. Stage-2's a input = stage-1's o1
// registers, re-staged through LDS only for the i-broadcast (no global trip).
// Row pad 10 floats: 8B-aligned b64 accesses, <=4-way banks.
// ---------------------------------------------------------------------------
__global__ __launch_bounds__(256, 8) void kRf(const float* __restrict__ rois_a,
                                              const float* __restrict__ rfb,
                                              const float* __restrict__ rois_c,
                                              float* __restrict__ out) {
    __shared__ __align__(16) float sa[64][10];
    __shared__ __align__(16) float sb[64][10];
    __shared__ __align__(16) float sc[64][10];

    const int bi = blockIdx.x;
    const int j  = (bi & 7) * 288 + (bi >> 3);  // XCD-chunked
    const int na = j >> 5;
    const int cb = (j & 31) * 8;
    const int t = threadIdx.x, lane = t & 63, w = t >> 6;
    const int cp = 2 * w;                       // this wave's channel pair
    const size_t base = (size_t)na * 64;

    float rc[2];
#pragma unroll
    for (int k = 0; k < 2; ++k) {
        int idx = t + 256 * k;
        int i = idx >> 3, cc = idx & 7;
        sa[i][cc] = rois_a[(base + i) * 256 + cb + cc];
        sb[i][cc] = rfb[(base + i) * 256 + cb + cc];
        rc[k]     = rois_c[(base + i) * 256 + cb + cc];
    }
    __syncthreads();

    // ---- stage 1: a = rois_a (sa), b = sampled (sb) ----
    const f32x2 a1 = *(const f32x2*)&sa[lane][cp];
    const f32x2 b1 = *(const f32x2*)&sb[lane][cp];
    f32x2 o1;
    {
        float mx0 = a1.x, mn0 = a1.x, mx1 = a1.y, mn1 = a1.y;
#pragma unroll
        for (int s = 32; s; s >>= 1) {
            mx0 = fmaxf(mx0, __shfl_xor(mx0, s, 64));
            mn0 = fminf(mn0, __shfl_xor(mn0, s, 64));
            mx1 = fmaxf(mx1, __shfl_xor(mx1, s, 64));
            mn1 = fminf(mn1, __shfl_xor(mn1, s, 64));
        }
        f32x2 m;
        m.x = b1.x > 0.f ? b1.x * mx0 : b1.x * mn0;
        m.y = b1.y > 0.f ? b1.y * mx1 : b1.y * mn1;
        const f32x2 bl2 = b1 * L2E;
        const f32x2 ml2 = -m * L2E;
        f32x2 den = {0.f, 0.f}, num = {0.f, 0.f};
#pragma unroll 8
        for (int i = 0; i < 64; ++i) {
            const f32x2 av = *(const f32x2*)&sa[i][cp];   // uniform -> broadcast
            f32x2 eg = av * bl2 + ml2;
            f32x2 e;
            e.x = __builtin_amdgcn_exp2f(eg.x);
            e.y = __builtin_amdgcn_exp2f(eg.y);
            den += e;
            num += e * av;
        }
        o1 = b1 + num / den;
    }
    __syncthreads();            // all waves done reading sa/sb

    // re-stage: sa <- o1 (for i-broadcast), sb <- rois_c
    *(f32x2*)&sa[lane][cp] = o1;
#pragma unroll
    for (int k = 0; k < 2; ++k) {
        int idx = t + 256 * k;
        sb[idx >> 3][idx & 7] = rc[k];
    }
    __syncthreads();

    // ---- stage 2: a = o1 (sa), b = rois_c (sb) ----
    {
        const f32x2 b2 = *(const f32x2*)&sb[lane][cp];
        float mx0 = o1.x, mn0 = o1.x, mx1 = o1.y, mn1 = o1.y;
#pragma unroll
        for (int s = 32; s; s >>= 1) {
            mx0 = fmaxf(mx0, __shfl_xor(mx0, s, 64));
            mn0 = fminf(mn0, __shfl_xor(mn0, s, 64));
            mx1 = fmaxf(mx1, __shfl_xor(mx1, s, 64));
            mn1 = fminf(mn1, __shfl_xor(mn1, s, 64));
        }
        f32x2 m;
        m.x = b2.x > 0.f ? b2.x * mx0 : b2.x * mn0;
        m.y = b2.y > 0.f ? b2.y * mx1 : b2.y * mn1;
        const f32x2 bl2 = b2 * L2E;
        const f32x2 ml2 = -m * L2E;
        f32x2 den = {0.f, 0.f}, num = {0.f, 0.f};
#pragma unroll 8
        for (int i = 0; i < 64; ++i) {
            const f32x2 av = *(const f32x2*)&sa[i][cp];   // uniform -> broadcast
            f32x2 eg = av * bl2 + ml2;
            f32x2 e;
            e.x = __builtin_amdgcn_exp2f(eg.x);
            e.y = __builtin_amdgcn_exp2f(eg.y);
            den += e;
            num += e * av;
        }
        *(f32x2*)&sc[lane][cp] = b2 + num / den;
    }
    __syncthreads();

#pragma unroll
    for (int k = 0; k < 2; ++k) {
        int idx = t + 256 * k;
        int i = idx >> 3, cc = idx & 7;
        out[(base + i) * 256 + cb + cc] = sc[i][cc];
    }
}

// ---------------------------------------------------------------------------
extern "C" void kernel_launch(void* const* d_in, const int* in_sizes, int n_in,
                              void* d_out, int out_size, void* d_ws, size_t ws_size,
                              hipStream_t stream) {
    // inputs: ori_feature_shape, rois_feature_a, feature_b, rois_feature_c, W_reg, b_reg
    const float* rois_a = (const float*)d_in[1];
    const float* feat   = (const float*)d_in[2];
    const float* rois_c = (const float*)d_in[3];
    const float* Wreg   = (const float*)d_in[4];
    const float* breg   = (const float*)d_in[5];
    float* out = (float*)d_out;
    float* partials = (float*)d_ws;                          // 512*2304 fl = 4.7 MB
    float* rfb      = (float*)d_ws + (size_t)NPOS * PSTRIDE; // M*C fl = 4.7 MB

    kA<<<dim3(NPOS * 4), dim3(256), 0, stream>>>(feat, Wreg, partials);
    kB<<<dim3(NPOS * 2), dim3(256), 0, stream>>>(feat, partials, breg, rfb);
    kRf<<<dim3(NJOBS2), dim3(256), 0, stream>>>(rois_a, rfb, rois_c, out);
}